// Round 19
// baseline (128.382 us; speedup 1.0000x reference)
//
#include <hip/hip_runtime.h>
#include <hip/hip_bf16.h>

#define S_LEN 2048
#define DIM_  2048
#define NH    32
#define NKV   8
#define HD    64

typedef __bf16 bf16x8 __attribute__((ext_vector_type(8)));
typedef __bf16 bf16x4 __attribute__((ext_vector_type(4)));
typedef float  f32x4  __attribute__((ext_vector_type(4)));

#define AS_GLOBAL(p) ((const __attribute__((address_space(1))) void*)(p))
#define AS_LDS(p)    ((__attribute__((address_space(3))) void*)(p))

__device__ __forceinline__ bf16x8 pack8(float4 a, float4 b) {
  bf16x8 r;
  r[0] = (__bf16)a.x; r[1] = (__bf16)a.y; r[2] = (__bf16)a.z; r[3] = (__bf16)a.w;
  r[4] = (__bf16)b.x; r[5] = (__bf16)b.y; r[6] = (__bf16)b.z; r[7] = (__bf16)b.w;
  return r;
}

// ---------------- fp32 -> bf16 conversion with CHUNK SWIZZLE ----------------
// 16B chunk j of each 2048-col matrix stored at j ^ ((j>>8)&7) (== ^row&7).
__global__ __launch_bounds__(256) void cvt_xw(
    const float* __restrict__ x,  const float* __restrict__ wq,
    const float* __restrict__ wk, const float* __restrict__ wv,
    const float* __restrict__ wo,
    __bf16* __restrict__ xb, __bf16* __restrict__ wb, __bf16* __restrict__ wob)
{
  const size_t stride = 458752;   // 1792 * 256
  size_t base = (size_t)blockIdx.x * 256 + threadIdx.x;
#pragma unroll
  for (int k = 0; k < 4; ++k) {
    size_t i = base + (size_t)k * stride;   // global chunk index
    const float* src; __bf16* dst; size_t j;
    if (i < 524288)       { src = x;  dst = xb;            j = i; }
    else if (i < 1048576) { src = wq; dst = wb;            j = i - 524288; }
    else if (i < 1179648) { src = wk; dst = wb + 4194304;  j = i - 1048576; }
    else if (i < 1310720) { src = wv; dst = wb + 5242880;  j = i - 1179648; }
    else                  { src = wo; dst = wob;           j = i - 1310720; }
    float4 f0 = ((const float4*)src)[j * 2];
    float4 f1 = ((const float4*)src)[j * 2 + 1];
    ((bf16x8*)dst)[j ^ ((j >> 8) & 7)] = pack8(f0, f1);
  }
}

// ---- 128x(NI*32)-out GEMM tile, BK=64, 256 thr / 4 waves, counted vmcnt ----
// Pipeline per iter: barrier A -> stage(t+1) -> vmcnt(4+NI) -> barrier B ->
// ds_read+MFMA(t). No vmcnt(0) in the loop. Wave = 64x(NI*16) out.
#define BK 64
#define TA_ELEMS 8192   // 128*64

__device__ __forceinline__ void stage_A(
    const __bf16* __restrict__ g, int row0, int k0, int ld, __bf16* lds)
{
  const int tid = threadIdx.x;
  const int wave = tid >> 6;
#pragma unroll
  for (int iss = 0; iss < 4; ++iss) {
    int off = (iss * 256 + tid) * 16;   // byte offset in 16 KB tile
    int r = off >> 7;                   // 128 B per row (64 bf16)
    int c = (off & 127) >> 1;           // physical bf16 col (pre-swizzled)
    __builtin_amdgcn_global_load_lds(
        AS_GLOBAL(g + (size_t)(row0 + r) * ld + k0 + c),
        AS_LDS(lds + iss * 2048 + wave * 512), 16, 0, 0);
  }
}

template<int CH>   // CH passes of 256 x 16B: stages CH*32 rows x 64 cols
__device__ __forceinline__ void stage_Bn(
    const __bf16* __restrict__ g, int row0, int k0, int ld, __bf16* lds)
{
  const int tid = threadIdx.x;
  const int wave = tid >> 6;
#pragma unroll
  for (int iss = 0; iss < CH; ++iss) {
    int off = (iss * 256 + tid) * 16;
    int r = off >> 7;
    int c = (off & 127) >> 1;
    __builtin_amdgcn_global_load_lds(
        AS_GLOBAL(g + (size_t)(row0 + r) * ld + k0 + c),
        AS_LDS(lds + iss * 2048 + wave * 512), 16, 0, 0);
  }
}

template<int NI>   // col-frags per wave: B tile = NI*32 rows, TB = NI*2048
__device__ __forceinline__ void gemm_mainloop(
    const __bf16* __restrict__ A, const __bf16* __restrict__ B,
    int row0, int col0, int lda, int ldb, int nt,
    __bf16* As, __bf16* Bs, f32x4 acc[4][NI])
{
  const int TB = NI * 2048;
  const int lane = threadIdx.x & 63;
  const int wave = threadIdx.x >> 6;
  const int wr = wave >> 1, wc = wave & 1;   // 2x2 wave grid
  const int fr = lane & 15, fg = lane >> 4;
  const int sw = fr & 7;                     // read-side chunk XOR

  stage_A(A, row0, 0, lda, As);
  stage_Bn<NI>(B, col0, 0, ldb, Bs);   // 4+NI vm ops/thread in flight

  for (int t = 0; t < nt; ++t) {
    const int cur = t & 1;

    // barrier A: all waves done READING buf cur^1 (tile t-1) last iter
    asm volatile("" ::: "memory");
    __builtin_amdgcn_s_barrier();
    asm volatile("" ::: "memory");

    // stage tile t+1 into buf cur^1 (clamped junk on last iter)
    const int tn = (t + 1 < nt) ? t + 1 : t;
    stage_A(A, row0, tn * BK, lda, As + (cur ^ 1) * TA_ELEMS);
    stage_Bn<NI>(B, col0, tn * BK, ldb, Bs + (cur ^ 1) * TB);

    // counted wait: own tile-t ops (4+NI older) landed; newer stay in flight
    if constexpr (NI == 3) asm volatile("s_waitcnt vmcnt(7)" ::: "memory");
    else                   asm volatile("s_waitcnt vmcnt(6)" ::: "memory");

    // barrier B: every wave confirmed its tile-t writes -> safe to read
    __builtin_amdgcn_s_barrier();
    asm volatile("" ::: "memory");

#pragma unroll
    for (int kk = 0; kk < 2; ++kk) {
      bf16x8 a[4], b[NI];
#pragma unroll
      for (int mi = 0; mi < 4; ++mi)
        a[mi] = *(const bf16x8*)(As + cur * TA_ELEMS +
                 (wr * 64 + mi * 16 + fr) * 64 + (((kk * 4 + fg) ^ sw) * 8));
#pragma unroll
      for (int ni = 0; ni < NI; ++ni)
        b[ni] = *(const bf16x8*)(Bs + cur * TB +
                 (wc * (NI * 16) + ni * 16 + fr) * 64 + (((kk * 4 + fg) ^ sw) * 8));
#pragma unroll
      for (int mi = 0; mi < 4; ++mi)
#pragma unroll
        for (int ni = 0; ni < NI; ++ni)
          acc[mi][ni] = __builtin_amdgcn_mfma_f32_16x16x32_bf16(a[mi], b[ni], acc[mi][ni], 0, 0, 0);
    }
  }
}

// ---------------- QKV projection (bf16-swz, 128x96 tiles, 512 blocks) -------
// Exactly 2 blocks/CU; wave = 64x48 (4x3 frags, 24 MFMA/K-step).
// K-RoPE fused into the epilogue (16-col slices never straddle Q/K/V splits).
__global__ __launch_bounds__(256) void qkv_gemm(
    const __bf16* __restrict__ xb, const __bf16* __restrict__ wb,
    const float* __restrict__ fc,
    __bf16* __restrict__ q_buf, __bf16* __restrict__ k_buf, __bf16* __restrict__ v_buf)
{
  __shared__ __bf16 As[2 * TA_ELEMS];   // 32 KB
  __shared__ __bf16 Bs[2 * 6144];       // 24 KB (96x64 dbuf)
  const int lane = threadIdx.x & 63;
  const int wave = threadIdx.x >> 6;
  const int wr = wave >> 1, wc = wave & 1;
  const int fr = lane & 15, fg = lane >> 4;

  const int lid = blockIdx.x;        // 0..511
  const int xcd = lid & 7;
  const int i   = lid >> 3;          // 0..63
  const int row0 = (i & 15) * 128;
  const int col0 = (xcd * 4 + (i >> 4)) * 96;   // per-XCD B slice 1.5 MB

  f32x4 acc[4][3] = {};
  gemm_mainloop<3>(xb, wb, row0, col0, DIM_, DIM_, DIM_ / BK, As, Bs, acc);

  const int rowg0 = row0 + wr * 64;
  const int colg0 = col0 + wc * 48;
#pragma unroll
  for (int mi = 0; mi < 4; ++mi) {
#pragma unroll
    for (int ni = 0; ni < 3; ++ni) {
#pragma unroll
      for (int j = 0; j < 4; ++j) {
        int row = rowg0 + mi * 16 + fg * 4 + j;
        int col = colg0 + ni * 16 + fr;
        float v = acc[mi][ni][j];
        if (col < 2048) {
          int h = col >> 6, d = col & 63;
          q_buf[((size_t)h * S_LEN + row) * HD + d] = (__bf16)v;
        } else if (col < 2560) {
          // K with fused RoPE (wave-uniform branch: 16-col slice in K range)
          int c = col - 2048, g = c >> 6, d = c & 63;
          float vp = __shfl_xor(v, 1, 64);
          const float* cs = fc + ((size_t)row * 32 + (d >> 1)) * 2;
          float cc = cs[0], ss = cs[1];
          float vr = (d & 1) ? (vp * ss + v * cc) : (v * cc - vp * ss);
          k_buf[((size_t)g * S_LEN + row) * HD + d] = (__bf16)vr;
        } else {
          int c = col - 2560, g = c >> 6, d = c & 63;
          v_buf[((size_t)g * HD + d) * S_LEN + row] = (__bf16)v;  // transposed
        }
      }
    }
  }
}

// ---------------- Output projection (bf16-swz, 512 blocks) ------------------
__global__ __launch_bounds__(256) void oproj_gemm(
    const __bf16* __restrict__ attn_buf, const __bf16* __restrict__ wob,
    float* __restrict__ out)
{
  __shared__ __bf16 As[2 * TA_ELEMS];
  __shared__ __bf16 Bs[2 * 4096];
  const int lane = threadIdx.x & 63;
  const int wave = threadIdx.x >> 6;
  const int wr = wave >> 1, wc = wave & 1;
  const int fr = lane & 15, fg = lane >> 4;

  const int lid = blockIdx.x;        // 0..511
  const int xcd = lid & 7;
  const int i   = lid >> 3;          // 0..63
  const int row0 = (i & 15) * 128;
  const int col0 = (xcd * 4 + (i >> 4)) * 64;

  f32x4 acc[4][2] = {};
  gemm_mainloop<2>(attn_buf, wob, row0, col0, DIM_, DIM_, DIM_ / BK, As, Bs, acc);

  const int rowg0 = row0 + wr * 64;
  const int colg0 = col0 + wc * 32;
#pragma unroll
  for (int mi = 0; mi < 4; ++mi)
#pragma unroll
    for (int ni = 0; ni < 2; ++ni)
#pragma unroll
      for (int j = 0; j < 4; ++j) {
        int row = rowg0 + mi * 16 + fg * 4 + j;
        int col = colg0 + ni * 16 + fr;
        out[(size_t)row * DIM_ + col] = acc[mi][ni][j];
      }
}

// ---------------- Flash attention (causal, GQA, swapped-QK, shared KV) ------
// 1-D grid 512, PAIRED dispatch. No max tracking (scores bounded ~2^10 <<
// f32 range); p = exp2(score); row-sum via ones-MFMA; single divide at end.
__global__ __launch_bounds__(512) void attn_kernel(
    const __bf16* __restrict__ q_buf, const __bf16* __restrict__ k_buf,
    const __bf16* __restrict__ v_buf, const float* __restrict__ fc,
    __bf16* __restrict__ attn_buf)
{
  __shared__ __align__(16) __bf16 Ks[2][64 * 64];   // 2 x 8 KB
  __shared__ __align__(16) __bf16 Vs[2][64 * 64];   // 2 x 8 KB (V^T: [d][kv])
  __shared__ __align__(16) __bf16 lds_p[8][16][72]; // per-wave P slab

  const int tid  = threadIdx.x;
  const int lane = tid & 63;
  const int wave = tid >> 6;
  const int n = blockIdx.x;
  const int qt = (n < 256) ? (15 - (n >> 5)) : ((n - 256) >> 5);
  const int h  = n & 31;
  const int g = h >> 2;             // NREP = 4
  const int r0 = qt * 128 + wave * 16;
  const int lrow = lane & 15;
  const int lgrp = lane >> 4;
  const int lk = lgrp * 8;

  const __bf16* qh = q_buf + (size_t)h * S_LEN * HD;
  const __bf16* kh = k_buf + (size_t)g * S_LEN * HD;
  const __bf16* vh = v_buf + (size_t)g * HD * S_LEN;

  const int sr   = tid >> 3;            // staging row 0..63
  const int scol = tid & 7;             // source 16B chunk
  const int dcol = scol ^ (sr & 7);     // swizzled dest chunk

  // ---- load Q fragment + RoPE with KS-folded coefficients ----
  const float KS = 0.125f * 1.44269504088896f;  // scale * log2(e)
  bf16x8 qa[2];
  const float* fcrow = fc + (size_t)(r0 + lrow) * 64;
#pragma unroll
  for (int kk = 0; kk < 2; ++kk) {
    qa[kk] = *(const bf16x8*)(qh + (size_t)(r0 + lrow) * HD + kk * 32 + lk);
    float4 cs0 = *(const float4*)(fcrow + (kk * 16 + lgrp * 4) * 2);
    float4 cs1 = *(const float4*)(fcrow + (kk * 16 + lgrp * 4) * 2 + 4);
    float cc[4] = {cs0.x * KS, cs0.z * KS, cs1.x * KS, cs1.z * KS};
    float ss[4] = {cs0.y * KS, cs0.w * KS, cs1.y * KS, cs1.w * KS};
#pragma unroll
    for (int pr = 0; pr < 4; ++pr) {
      float x1 = (float)qa[kk][2 * pr], x2 = (float)qa[kk][2 * pr + 1];
      qa[kk][2 * pr]     = (__bf16)(x1 * cc[pr] - x2 * ss[pr]);
      qa[kk][2 * pr + 1] = (__bf16)(x1 * ss[pr] + x2 * cc[pr]);
    }
  }

  bf16x8 vones;
#pragma unroll
  for (int i = 0; i < 8; ++i) vones[i] = (__bf16)1.0f;

  f32x4 oacc[5] = {};   // [0..3] = O columns, [4] = row-sum (P x ones)

  const int nt = 2 * qt + 2;

  {
    uint4 k0 = *(const uint4*)(kh + (size_t)sr * HD + scol * 8);
    uint4 v0 = *(const uint4*)(vh + (size_t)sr * S_LEN + scol * 8);
    *(uint4*)(&Ks[0][sr * 64 + dcol * 8]) = k0;
    *(uint4*)(&Vs[0][sr * 64 + dcol * 8]) = v0;
  }
  __syncthreads();

  for (int t = 0; t < nt; ++t) {
    const int cur = t & 1;
    const int t0 = t * 64;

    const int tn0 = (t + 1 < nt ? t + 1 : t) * 64;
    uint4 kreg = *(const uint4*)(kh + (size_t)(tn0 + sr) * HD + scol * 8);
    uint4 vreg = *(const uint4*)(vh + (size_t)sr * S_LEN + tn0 + scol * 8);

    const int dmax = r0 + 15 - t0;
    if (dmax >= 0) {
      f32x4 sc[4] = {};
      const int cmax = dmax >> 4;
      __builtin_amdgcn_s_setprio(1);
#pragma unroll
      for (int c = 0; c < 4; ++c) {
        if (c <= cmax) {
#pragma unroll
          for (int kk = 0; kk < 2; ++kk) {
            bf16x8 ka = *(const bf16x8*)(
                &Ks[cur][(c * 16 + lrow) * 64 + (((kk * 4 + lgrp) ^ (lrow & 7)) * 8)]);
            sc[c] = __builtin_amdgcn_mfma_f32_16x16x32_bf16(ka, qa[kk], sc[c], 0, 0, 0);
          }
        }
      }
      __builtin_amdgcn_s_setprio(0);

      // ---- p = exp2(score) directly (no max tracking) ----
      float p[16];
      const int q = r0 + lrow;
      if (t0 + 63 <= r0) {
#pragma unroll
        for (int c = 0; c < 4; ++c)
#pragma unroll
          for (int j = 0; j < 4; ++j)
            p[c * 4 + j] = __builtin_amdgcn_exp2f(sc[c][j]);
      } else {
#pragma unroll
        for (int c = 0; c < 4; ++c)
#pragma unroll
          for (int j = 0; j < 4; ++j) {
            int kv = t0 + c * 16 + lgrp * 4 + j;
            p[c * 4 + j] = (kv <= q) ? __builtin_amdgcn_exp2f(sc[c][j]) : 0.0f;
          }
      }

#pragma unroll
      for (int c = 0; c < 4; ++c)
#pragma unroll
        for (int e = 0; e < 2; ++e) {
          union { __bf16 hh[2]; unsigned u; } pk;
          pk.hh[0] = (__bf16)p[c * 4 + 2 * e];
          pk.hh[1] = (__bf16)p[c * 4 + 2 * e + 1];
          *(unsigned*)&lds_p[wave][lrow][c * 16 + lgrp * 4 + 2 * e] = pk.u;
        }
      asm volatile("s_waitcnt lgkmcnt(0)" ::: "memory");

      bf16x8 pa0 = *(const bf16x8*)&lds_p[wave][lrow][lk];
      __builtin_amdgcn_s_setprio(1);
#pragma unroll
      for (int nf = 0; nf < 4; ++nf) {
        bf16x8 vb = *(const bf16x8*)(
            &Vs[cur][(nf * 16 + lrow) * 64 + ((lgrp ^ (lrow & 7)) * 8)]);
        oacc[nf] = __builtin_amdgcn_mfma_f32_16x16x32_bf16(pa0, vb, oacc[nf], 0, 0, 0);
      }
      oacc[4] = __builtin_amdgcn_mfma_f32_16x16x32_bf16(pa0, vones, oacc[4], 0, 0, 0);
      __builtin_amdgcn_s_setprio(0);
      if (dmax >= 32) {
        bf16x8 pa1 = *(const bf16x8*)&lds_p[wave][lrow][32 + lk];
        __builtin_amdgcn_s_setprio(1);
#pragma unroll
        for (int nf = 0; nf < 4; ++nf) {
          bf16x8 vb = *(const bf16x8*)(
              &Vs[cur][(nf * 16 + lrow) * 64 + (((4 + lgrp) ^ (lrow & 7)) * 8)]);
          oacc[nf] = __builtin_amdgcn_mfma_f32_16x16x32_bf16(pa1, vb, oacc[nf], 0, 0, 0);
        }
        oacc[4] = __builtin_amdgcn_mfma_f32_16x16x32_bf16(pa1, vones, oacc[4], 0, 0, 0);
        __builtin_amdgcn_s_setprio(0);
      }
    }

    *(uint4*)(&Ks[cur ^ 1][sr * 64 + dcol * 8]) = kreg;
    *(uint4*)(&Vs[cur ^ 1][sr * 64 + dcol * 8]) = vreg;
    __syncthreads();
  }

  // ---- epilogue: divide by row-sum (row layout — no shuffle); swz store ----
  float rlr[4];
#pragma unroll
  for (int j = 0; j < 4; ++j)
    rlr[j] = 1.0f / oacc[4][j];
#pragma unroll
  for (int nf = 0; nf < 4; ++nf)
#pragma unroll
    for (int j = 0; j < 4; ++j) {
      int row = r0 + lgrp * 4 + j;
      int col = h * HD + nf * 16 + lrow;
      int ch  = (((col >> 3) & 7) ^ (row & 7));
      int cols = (col & 7) | (ch << 3) | (col & ~63);
      attn_buf[(size_t)row * (NH * HD) + cols] =
          (__bf16)(oacc[nf][j] * rlr[j]);
    }
}

extern "C" void kernel_launch(void* const* d_in, const int* in_sizes, int n_in,
                              void* d_out, int out_size, void* d_ws, size_t ws_size,
                              hipStream_t stream)
{
  const float* x  = (const float*)d_in[0];
  const float* wq = (const float*)d_in[1];
  const float* wk = (const float*)d_in[2];
  const float* wv = (const float*)d_in[3];
  const float* wo = (const float*)d_in[4];
  const float* fc = (const float*)d_in[5];
  float* out = (float*)d_out;

  char* ws = (char*)d_ws;
  __bf16* q_buf    = (__bf16*)(ws);                       //  8 MB [NH][S][HD]
  __bf16* k_buf    = (__bf16*)(ws +  8u * 1024 * 1024);   //  2 MB [NKV][S][HD]
  __bf16* v_buf    = (__bf16*)(ws + 10u * 1024 * 1024);   //  2 MB [NKV][HD][S]
  __bf16* attn_buf = (__bf16*)(ws + 12u * 1024 * 1024);   //  8 MB [S][NH*HD] swz
  __bf16* xb       = (__bf16*)(ws + 20u * 1024 * 1024);   //  8 MB [S][DIM] swz
  __bf16* wb       = (__bf16*)(ws + 28u * 1024 * 1024);   // 12 MB [3072][DIM] swz
  __bf16* wob      = (__bf16*)(ws + 40u * 1024 * 1024);   //  8 MB [DIM][DIM] swz

  cvt_xw<<<dim3(1792), 256, 0, stream>>>(x, wq, wk, wv, wo, xb, wb, wob);
  qkv_gemm<<<dim3(512), 256, 0, stream>>>(xb, wb, fc, q_buf, k_buf, v_buf);
  attn_kernel<<<dim3(512), 512, 0, stream>>>(q_buf, k_buf, v_buf, fc, attn_buf);
  oproj_gemm<<<dim3(512), 256, 0, stream>>>(attn_buf, wob, out);
}

// Round 20
// 121.603 us; speedup vs baseline: 1.0557x; 1.0557x over previous
//
#include <hip/hip_runtime.h>
#include <hip/hip_bf16.h>

#define S_LEN 2048
#define DIM_  2048
#define NH    32
#define NKV   8
#define HD    64

typedef __bf16 bf16x8 __attribute__((ext_vector_type(8)));
typedef __bf16 bf16x4 __attribute__((ext_vector_type(4)));
typedef float  f32x4  __attribute__((ext_vector_type(4)));

#define AS_GLOBAL(p) ((const __attribute__((address_space(1))) void*)(p))
#define AS_LDS(p)    ((__attribute__((address_space(3))) void*)(p))

__device__ __forceinline__ bf16x8 pack8(float4 a, float4 b) {
  bf16x8 r;
  r[0] = (__bf16)a.x; r[1] = (__bf16)a.y; r[2] = (__bf16)a.z; r[3] = (__bf16)a.w;
  r[4] = (__bf16)b.x; r[5] = (__bf16)b.y; r[6] = (__bf16)b.z; r[7] = (__bf16)b.w;
  return r;
}

// ---------------- fp32 -> bf16 conversion with CHUNK SWIZZLE ----------------
// 16B chunk j of each 2048-col matrix stored at j ^ ((j>>8)&7) (== ^row&7).
__global__ __launch_bounds__(256) void cvt_xw(
    const float* __restrict__ x,  const float* __restrict__ wq,
    const float* __restrict__ wk, const float* __restrict__ wv,
    const float* __restrict__ wo,
    __bf16* __restrict__ xb, __bf16* __restrict__ wb, __bf16* __restrict__ wob)
{
  const size_t stride = 458752;   // 1792 * 256
  size_t base = (size_t)blockIdx.x * 256 + threadIdx.x;
#pragma unroll
  for (int k = 0; k < 4; ++k) {
    size_t i = base + (size_t)k * stride;   // global chunk index
    const float* src; __bf16* dst; size_t j;
    if (i < 524288)       { src = x;  dst = xb;            j = i; }
    else if (i < 1048576) { src = wq; dst = wb;            j = i - 524288; }
    else if (i < 1179648) { src = wk; dst = wb + 4194304;  j = i - 1048576; }
    else if (i < 1310720) { src = wv; dst = wb + 5242880;  j = i - 1179648; }
    else                  { src = wo; dst = wob;           j = i - 1310720; }
    float4 f0 = ((const float4*)src)[j * 2];
    float4 f1 = ((const float4*)src)[j * 2 + 1];
    ((bf16x8*)dst)[j ^ ((j >> 8) & 7)] = pack8(f0, f1);
  }
}

// ------ 128x64-out GEMM tile, BK=64, 256 thr / 4 waves, global_load_lds -----
// T4 counted-vmcnt pipeline, race-free 2-buffer form:
//   barrier A -> stage(t+1) -> vmcnt(6) -> barrier B -> ds_read+MFMA(t)
// No vmcnt(0) in the loop: the 6 next-tile loads stay in flight under MFMA.
#define BK 64
#define TA_ELEMS 8192   // 128*64
#define TB_ELEMS 4096   //  64*64

__device__ __forceinline__ void stage_A(
    const __bf16* __restrict__ g, int row0, int k0, int ld, __bf16* lds)
{
  const int tid = threadIdx.x;
  const int wave = tid >> 6;
#pragma unroll
  for (int iss = 0; iss < 4; ++iss) {
    int off = (iss * 256 + tid) * 16;   // byte offset in 16 KB tile
    int r = off >> 7;                   // 128 B per row (64 bf16)
    int c = (off & 127) >> 1;           // physical bf16 col (pre-swizzled)
    __builtin_amdgcn_global_load_lds(
        AS_GLOBAL(g + (size_t)(row0 + r) * ld + k0 + c),
        AS_LDS(lds + iss * 2048 + wave * 512), 16, 0, 0);
  }
}

__device__ __forceinline__ void stage_B(
    const __bf16* __restrict__ g, int row0, int k0, int ld, __bf16* lds)
{
  const int tid = threadIdx.x;
  const int wave = tid >> 6;
#pragma unroll
  for (int iss = 0; iss < 2; ++iss) {
    int off = (iss * 256 + tid) * 16;
    int r = off >> 7;
    int c = (off & 127) >> 1;
    __builtin_amdgcn_global_load_lds(
        AS_GLOBAL(g + (size_t)(row0 + r) * ld + k0 + c),
        AS_LDS(lds + iss * 2048 + wave * 512), 16, 0, 0);
  }
}

__device__ __forceinline__ void gemm_mainloop(
    const __bf16* __restrict__ A, const __bf16* __restrict__ B,
    int row0, int col0, int lda, int ldb, int nt,
    __bf16* As, __bf16* Bs, f32x4 acc[4][2])
{
  const int lane = threadIdx.x & 63;
  const int wave = threadIdx.x >> 6;
  const int wr = wave >> 1, wc = wave & 1;   // 2x2 wave grid
  const int fr = lane & 15, fg = lane >> 4;
  const int sw = fr & 7;                     // read-side chunk XOR

  stage_A(A, row0, 0, lda, As);
  stage_B(B, col0, 0, ldb, Bs);   // 6 vm ops/thread in flight

  for (int t = 0; t < nt; ++t) {
    const int cur = t & 1;

    // barrier A: all waves done READING buf cur^1 (tile t-1) last iter
    asm volatile("" ::: "memory");
    __builtin_amdgcn_s_barrier();
    asm volatile("" ::: "memory");

    // stage tile t+1 into buf cur^1 (clamped junk on last iter)
    const int tn = (t + 1 < nt) ? t + 1 : t;
    stage_A(A, row0, tn * BK, lda, As + (cur ^ 1) * TA_ELEMS);
    stage_B(B, col0, tn * BK, ldb, Bs + (cur ^ 1) * TB_ELEMS);

    // counted wait: own tile-t ops (6 older) landed; 6 newer stay in flight
    asm volatile("s_waitcnt vmcnt(6)" ::: "memory");

    // barrier B: every wave confirmed its tile-t writes -> safe to read
    __builtin_amdgcn_s_barrier();
    asm volatile("" ::: "memory");

#pragma unroll
    for (int kk = 0; kk < 2; ++kk) {
      bf16x8 a[4], b[2];
#pragma unroll
      for (int mi = 0; mi < 4; ++mi)
        a[mi] = *(const bf16x8*)(As + cur * TA_ELEMS +
                 (wr * 64 + mi * 16 + fr) * 64 + (((kk * 4 + fg) ^ sw) * 8));
#pragma unroll
      for (int ni = 0; ni < 2; ++ni)
        b[ni] = *(const bf16x8*)(Bs + cur * TB_ELEMS +
                 (wc * 32 + ni * 16 + fr) * 64 + (((kk * 4 + fg) ^ sw) * 8));
#pragma unroll
      for (int mi = 0; mi < 4; ++mi)
#pragma unroll
        for (int ni = 0; ni < 2; ++ni)
          acc[mi][ni] = __builtin_amdgcn_mfma_f32_16x16x32_bf16(a[mi], b[ni], acc[mi][ni], 0, 0, 0);
    }
  }
}

// ---------------- QKV projection (bf16-swz, 768 blocks = 3/CU) --------------
// K-RoPE fused into the epilogue.
__global__ __launch_bounds__(256) void qkv_gemm(
    const __bf16* __restrict__ xb, const __bf16* __restrict__ wb,
    const float* __restrict__ fc,
    __bf16* __restrict__ q_buf, __bf16* __restrict__ k_buf, __bf16* __restrict__ v_buf)
{
  __shared__ __bf16 As[2 * TA_ELEMS];   // 32 KB
  __shared__ __bf16 Bs[2 * TB_ELEMS];   // 16 KB
  const int lane = threadIdx.x & 63;
  const int wave = threadIdx.x >> 6;
  const int wr = wave >> 1, wc = wave & 1;
  const int fr = lane & 15, fg = lane >> 4;

  const int lid = blockIdx.x;        // 0..767
  const int xcd = lid & 7;
  const int i   = lid >> 3;          // 0..95
  const int row0 = (i & 15) * 128;
  const int col0 = (xcd * 6 + (i >> 4)) * 64;

  f32x4 acc[4][2] = {};
  gemm_mainloop(xb, wb, row0, col0, DIM_, DIM_, DIM_ / BK, As, Bs, acc);

  const int rowg0 = row0 + wr * 64;
  const int colg0 = col0 + wc * 32;
#pragma unroll
  for (int mi = 0; mi < 4; ++mi) {
#pragma unroll
    for (int ni = 0; ni < 2; ++ni) {
#pragma unroll
      for (int j = 0; j < 4; ++j) {
        int row = rowg0 + mi * 16 + fg * 4 + j;
        int col = colg0 + ni * 16 + fr;
        float v = acc[mi][ni][j];
        if (col < 2048) {
          int h = col >> 6, d = col & 63;
          q_buf[((size_t)h * S_LEN + row) * HD + d] = (__bf16)v;
        } else if (col < 2560) {
          // K with fused RoPE (wave-uniform branch: 16-col slice in K range)
          int c = col - 2048, g = c >> 6, d = c & 63;
          float vp = __shfl_xor(v, 1, 64);
          const float* cs = fc + ((size_t)row * 32 + (d >> 1)) * 2;
          float cc = cs[0], ss = cs[1];
          float vr = (d & 1) ? (vp * ss + v * cc) : (v * cc - vp * ss);
          k_buf[((size_t)g * S_LEN + row) * HD + d] = (__bf16)vr;
        } else {
          int c = col - 2560, g = c >> 6, d = c & 63;
          v_buf[((size_t)g * HD + d) * S_LEN + row] = (__bf16)v;  // transposed
        }
      }
    }
  }
}

// ---------------- Output projection (bf16-swz, 512 blocks) ------------------
__global__ __launch_bounds__(256) void oproj_gemm(
    const __bf16* __restrict__ attn_buf, const __bf16* __restrict__ wob,
    float* __restrict__ out)
{
  __shared__ __bf16 As[2 * TA_ELEMS];
  __shared__ __bf16 Bs[2 * TB_ELEMS];
  const int lane = threadIdx.x & 63;
  const int wave = threadIdx.x >> 6;
  const int wr = wave >> 1, wc = wave & 1;
  const int fr = lane & 15, fg = lane >> 4;

  const int lid = blockIdx.x;        // 0..511
  const int xcd = lid & 7;
  const int i   = lid >> 3;          // 0..63
  const int row0 = (i & 15) * 128;
  const int col0 = (xcd * 4 + (i >> 4)) * 64;

  f32x4 acc[4][2] = {};
  gemm_mainloop(attn_buf, wob, row0, col0, DIM_, DIM_, DIM_ / BK, As, Bs, acc);

  const int rowg0 = row0 + wr * 64;
  const int colg0 = col0 + wc * 32;
#pragma unroll
  for (int mi = 0; mi < 4; ++mi)
#pragma unroll
    for (int ni = 0; ni < 2; ++ni)
#pragma unroll
      for (int j = 0; j < 4; ++j) {
        int row = rowg0 + mi * 16 + fg * 4 + j;
        int col = colg0 + ni * 16 + fr;
        out[(size_t)row * DIM_ + col] = acc[mi][ni][j];
      }
}

// ---------------- Flash attention (causal, GQA, swapped-QK, shared KV) ------
// 1-D grid 512, PAIRED dispatch. No max tracking (scores bounded ~2^10 <<
// f32 range); p = exp2(score); row-sum via ones-MFMA; single divide at end.
__global__ __launch_bounds__(512) void attn_kernel(
    const __bf16* __restrict__ q_buf, const __bf16* __restrict__ k_buf,
    const __bf16* __restrict__ v_buf, const float* __restrict__ fc,
    __bf16* __restrict__ attn_buf)
{
  __shared__ __align__(16) __bf16 Ks[2][64 * 64];   // 2 x 8 KB
  __shared__ __align__(16) __bf16 Vs[2][64 * 64];   // 2 x 8 KB (V^T: [d][kv])
  __shared__ __align__(16) __bf16 lds_p[8][16][72]; // per-wave P slab

  const int tid  = threadIdx.x;
  const int lane = tid & 63;
  const int wave = tid >> 6;
  const int n = blockIdx.x;
  const int qt = (n < 256) ? (15 - (n >> 5)) : ((n - 256) >> 5);
  const int h  = n & 31;
  const int g = h >> 2;             // NREP = 4
  const int r0 = qt * 128 + wave * 16;
  const int lrow = lane & 15;
  const int lgrp = lane >> 4;
  const int lk = lgrp * 8;

  const __bf16* qh = q_buf + (size_t)h * S_LEN * HD;
  const __bf16* kh = k_buf + (size_t)g * S_LEN * HD;
  const __bf16* vh = v_buf + (size_t)g * HD * S_LEN;

  const int sr   = tid >> 3;            // staging row 0..63
  const int scol = tid & 7;             // source 16B chunk
  const int dcol = scol ^ (sr & 7);     // swizzled dest chunk

  // ---- load Q fragment + RoPE with KS-folded coefficients ----
  const float KS = 0.125f * 1.44269504088896f;  // scale * log2(e)
  bf16x8 qa[2];
  const float* fcrow = fc + (size_t)(r0 + lrow) * 64;
#pragma unroll
  for (int kk = 0; kk < 2; ++kk) {
    qa[kk] = *(const bf16x8*)(qh + (size_t)(r0 + lrow) * HD + kk * 32 + lk);
    float4 cs0 = *(const float4*)(fcrow + (kk * 16 + lgrp * 4) * 2);
    float4 cs1 = *(const float4*)(fcrow + (kk * 16 + lgrp * 4) * 2 + 4);
    float cc[4] = {cs0.x * KS, cs0.z * KS, cs1.x * KS, cs1.z * KS};
    float ss[4] = {cs0.y * KS, cs0.w * KS, cs1.y * KS, cs1.w * KS};
#pragma unroll
    for (int pr = 0; pr < 4; ++pr) {
      float x1 = (float)qa[kk][2 * pr], x2 = (float)qa[kk][2 * pr + 1];
      qa[kk][2 * pr]     = (__bf16)(x1 * cc[pr] - x2 * ss[pr]);
      qa[kk][2 * pr + 1] = (__bf16)(x1 * ss[pr] + x2 * cc[pr]);
    }
  }

  bf16x8 vones;
#pragma unroll
  for (int i = 0; i < 8; ++i) vones[i] = (__bf16)1.0f;

  f32x4 oacc[5] = {};   // [0..3] = O columns, [4] = row-sum (P x ones)

  const int nt = 2 * qt + 2;

  {
    uint4 k0 = *(const uint4*)(kh + (size_t)sr * HD + scol * 8);
    uint4 v0 = *(const uint4*)(vh + (size_t)sr * S_LEN + scol * 8);
    *(uint4*)(&Ks[0][sr * 64 + dcol * 8]) = k0;
    *(uint4*)(&Vs[0][sr * 64 + dcol * 8]) = v0;
  }
  __syncthreads();

  for (int t = 0; t < nt; ++t) {
    const int cur = t & 1;
    const int t0 = t * 64;

    const int tn0 = (t + 1 < nt ? t + 1 : t) * 64;
    uint4 kreg = *(const uint4*)(kh + (size_t)(tn0 + sr) * HD + scol * 8);
    uint4 vreg = *(const uint4*)(vh + (size_t)sr * S_LEN + tn0 + scol * 8);

    const int dmax = r0 + 15 - t0;
    if (dmax >= 0) {
      f32x4 sc[4] = {};
      const int cmax = dmax >> 4;
      __builtin_amdgcn_s_setprio(1);
#pragma unroll
      for (int c = 0; c < 4; ++c) {
        if (c <= cmax) {
#pragma unroll
          for (int kk = 0; kk < 2; ++kk) {
            bf16x8 ka = *(const bf16x8*)(
                &Ks[cur][(c * 16 + lrow) * 64 + (((kk * 4 + lgrp) ^ (lrow & 7)) * 8)]);
            sc[c] = __builtin_amdgcn_mfma_f32_16x16x32_bf16(ka, qa[kk], sc[c], 0, 0, 0);
          }
        }
      }
      __builtin_amdgcn_s_setprio(0);

      // ---- p = exp2(score) directly (no max tracking) ----
      float p[16];
      const int q = r0 + lrow;
      if (t0 + 63 <= r0) {
#pragma unroll
        for (int c = 0; c < 4; ++c)
#pragma unroll
          for (int j = 0; j < 4; ++j)
            p[c * 4 + j] = __builtin_amdgcn_exp2f(sc[c][j]);
      } else {
#pragma unroll
        for (int c = 0; c < 4; ++c)
#pragma unroll
          for (int j = 0; j < 4; ++j) {
            int kv = t0 + c * 16 + lgrp * 4 + j;
            p[c * 4 + j] = (kv <= q) ? __builtin_amdgcn_exp2f(sc[c][j]) : 0.0f;
          }
      }

#pragma unroll
      for (int c = 0; c < 4; ++c)
#pragma unroll
        for (int e = 0; e < 2; ++e) {
          union { __bf16 hh[2]; unsigned u; } pk;
          pk.hh[0] = (__bf16)p[c * 4 + 2 * e];
          pk.hh[1] = (__bf16)p[c * 4 + 2 * e + 1];
          *(unsigned*)&lds_p[wave][lrow][c * 16 + lgrp * 4 + 2 * e] = pk.u;
        }
      asm volatile("s_waitcnt lgkmcnt(0)" ::: "memory");

      bf16x8 pa0 = *(const bf16x8*)&lds_p[wave][lrow][lk];
      __builtin_amdgcn_s_setprio(1);
#pragma unroll
      for (int nf = 0; nf < 4; ++nf) {
        bf16x8 vb = *(const bf16x8*)(
            &Vs[cur][(nf * 16 + lrow) * 64 + ((lgrp ^ (lrow & 7)) * 8)]);
        oacc[nf] = __builtin_amdgcn_mfma_f32_16x16x32_bf16(pa0, vb, oacc[nf], 0, 0, 0);
      }
      oacc[4] = __builtin_amdgcn_mfma_f32_16x16x32_bf16(pa0, vones, oacc[4], 0, 0, 0);
      __builtin_amdgcn_s_setprio(0);
      if (dmax >= 32) {
        bf16x8 pa1 = *(const bf16x8*)&lds_p[wave][lrow][32 + lk];
        __builtin_amdgcn_s_setprio(1);
#pragma unroll
        for (int nf = 0; nf < 4; ++nf) {
          bf16x8 vb = *(const bf16x8*)(
              &Vs[cur][(nf * 16 + lrow) * 64 + (((4 + lgrp) ^ (lrow & 7)) * 8)]);
          oacc[nf] = __builtin_amdgcn_mfma_f32_16x16x32_bf16(pa1, vb, oacc[nf], 0, 0, 0);
        }
        oacc[4] = __builtin_amdgcn_mfma_f32_16x16x32_bf16(pa1, vones, oacc[4], 0, 0, 0);
        __builtin_amdgcn_s_setprio(0);
      }
    }

    *(uint4*)(&Ks[cur ^ 1][sr * 64 + dcol * 8]) = kreg;
    *(uint4*)(&Vs[cur ^ 1][sr * 64 + dcol * 8]) = vreg;
    __syncthreads();
  }

  // ---- epilogue: divide by row-sum (row layout — no shuffle); swz store ----
  float rlr[4];
#pragma unroll
  for (int j = 0; j < 4; ++j)
    rlr[j] = 1.0f / oacc[4][j];
#pragma unroll
  for (int nf = 0; nf < 4; ++nf)
#pragma unroll
    for (int j = 0; j < 4; ++j) {
      int row = r0 + lgrp * 4 + j;
      int col = h * HD + nf * 16 + lrow;
      int ch  = (((col >> 3) & 7) ^ (row & 7));
      int cols = (col & 7) | (ch << 3) | (col & ~63);
      attn_buf[(size_t)row * (NH * HD) + cols] =
          (__bf16)(oacc[nf][j] * rlr[j]);
    }
}

extern "C" void kernel_launch(void* const* d_in, const int* in_sizes, int n_in,
                              void* d_out, int out_size, void* d_ws, size_t ws_size,
                              hipStream_t stream)
{
  const float* x  = (const float*)d_in[0];
  const float* wq = (const float*)d_in[1];
  const float* wk = (const float*)d_in[2];
  const float* wv = (const float*)d_in[3];
  const float* wo = (const float*)d_in[4];
  const float* fc = (const float*)d_in[5];
  float* out = (float*)d_out;

  char* ws = (char*)d_ws;
  __bf16* q_buf    = (__bf16*)(ws);                       //  8 MB [NH][S][HD]
  __bf16* k_buf    = (__bf16*)(ws +  8u * 1024 * 1024);   //  2 MB [NKV][S][HD]
  __bf16* v_buf    = (__bf16*)(ws + 10u * 1024 * 1024);   //  2 MB [NKV][HD][S]
  __bf16* attn_buf = (__bf16*)(ws + 12u * 1024 * 1024);   //  8 MB [S][NH*HD] swz
  __bf16* xb       = (__bf16*)(ws + 20u * 1024 * 1024);   //  8 MB [S][DIM] swz
  __bf16* wb       = (__bf16*)(ws + 28u * 1024 * 1024);   // 12 MB [3072][DIM] swz
  __bf16* wob      = (__bf16*)(ws + 40u * 1024 * 1024);   //  8 MB [DIM][DIM] swz

  cvt_xw<<<dim3(1792), 256, 0, stream>>>(x, wq, wk, wv, wo, xb, wb, wob);
  qkv_gemm<<<dim3(768), 256, 0, stream>>>(xb, wb, fc, q_buf, k_buf, v_buf);
  attn_kernel<<<dim3(512), 512, 0, stream>>>(q_buf, k_buf, v_buf, fc, attn_buf);
  oproj_gemm<<<dim3(512), 256, 0, stream>>>(attn_buf, wob, out);
}